// Round 1
// baseline (328.266 us; speedup 1.0000x reference)
//
#include <hip/hip_runtime.h>
#include <math.h>

#define Bn 8
#define Nn 262144
#define Kk 256
#define Dd 16
#define MCAP 4096
#define MSEL 1024
#define CHUNK 4096
#define ASTRIDE 17

// weights
#define W_ATTR 1.0f
#define W_REP 1.0f
#define W_BPOS 10.0f
#define W_BNEG 3.0f
#define W_BBG 6.0f
#define W_MARG 10.0f
// THR=0.5 MARGIN=0.3 -> THR+MARGIN=0.8, THR-MARGIN=0.2
#define ALPHA_F 0.75f

// workspace word offsets
#define OFF_SUMF   0                          // [B*K] float: sum focal over valid cps
#define OFF_CNT    (Bn*Kk)                    // [B*K] int: cp count per seg
#define OFF_INST   (2*Bn*Kk)                  // [B*K] int: instance size
#define OFF_FIRST  (3*Bn*Kk)                  // [B*K] int: min cp index (0x7FFFFFFF sentinel)
#define OFF_SD2    (4*Bn*Kk)                  // [B*K] float: sum d2
#define OFF_ANCH   (5*Bn*Kk)                  // [B*K*D] float anchors
#define OFF_SCAL   (OFF_ANCH + Bn*Kk*Dd)      // [B*16]: 0 ce0_ncp 1 rpos 2 rneg 3 ce0_bg 4 n_cp 5 n_bg (floats) 6 mv(int) 7 ok(int) 8 beta_loss 9 repulsion
#define OFF_CPIDX  (OFF_SCAL + Bn*16)         // [B*MCAP] int
#define OFF_MODE   (OFF_CPIDX + Bn*MCAP)      // [1] int: 0 = 4-byte elements, 1 = byte elements
#define WS_WORDS   (OFF_MODE + 1)

__global__ void k_init(int* wsi) {
  int stride = gridDim.x * blockDim.x;
  for (int i = blockIdx.x * blockDim.x + threadIdx.x; i < WS_WORDS; i += stride) {
    int v = 0;
    if (i >= OFF_FIRST && i < OFF_FIRST + Bn * Kk) v = 0x7FFFFFFF;
    wsi[i] = v;
  }
}

// Detect is_cp element width. If stored as int32 (0/1) or float32 (0/1.0f),
// every 4-byte word is 0, 1, or 0x3F800000. If stored as packed bytes (0/1),
// with ~2k set bytes some word is >1 and never equals 0x3F800000
// (bytes are only 0/1). Scan B*N/4 words: in-bounds under both layouts.
__global__ void k_detect(const unsigned int* w, int* wsi) {
  int stride = gridDim.x * blockDim.x;
  int bad = 0;
  for (int i = blockIdx.x * blockDim.x + threadIdx.x; i < (Bn * Nn) / 4; i += stride) {
    unsigned int x = w[i];
    if (x > 1u && x != 0x3F800000u) bad = 1;
  }
  if (bad) atomicOr(&wsi[OFF_MODE], 1);
}

__global__ __launch_bounds__(256) void k_pass1(const float* __restrict__ beta,
                                               const int* __restrict__ sid,
                                               const void* __restrict__ cpp,
                                               float* wsf, int* wsi) {
  const int b = blockIdx.y;
  const int tid = threadIdx.x;
  __shared__ float ls_sumf[Kk];
  __shared__ int ls_cnt[Kk], ls_inst[Kk], ls_first[Kk];
  __shared__ float sr[4][4];
  __shared__ float si[4][2];
  ls_sumf[tid] = 0.f; ls_cnt[tid] = 0; ls_inst[tid] = 0; ls_first[tid] = 0x7FFFFFFF;
  __syncthreads();
  const int mode = wsi[OFF_MODE];
  const int base = b * Nn;
  const int i0 = blockIdx.x * CHUNK;
  float a_ce0n = 0.f, a_rpos = 0.f, a_rneg = 0.f, a_ce0b = 0.f;
  float a_ncp = 0.f, a_nbg = 0.f;
  for (int it = 0; it < CHUNK / 256; ++it) {
    int i = i0 + it * 256 + tid;
    int s = sid[base + i];
    bool cp;
    if (mode) cp = ((const unsigned char*)cpp)[base + i] != 0;
    else      cp = ((const unsigned int*)cpp)[base + i] != 0u;
    float x = beta[base + i];
    float p = 1.f / (1.f + __expf(-x));
    float ax = fabsf(x);
    float sp = log1pf(__expf(-ax));
    float ce1 = sp + fmaxf(-x, 0.f);   // softplus(-x): BCE target 1
    float ce0 = sp + fmaxf(x, 0.f);    // softplus(x):  BCE target 0
    if (cp) { a_rpos += fmaxf(0.8f - p, 0.f); a_ncp += 1.f; }
    else { a_ce0n += ce0; a_rneg += fmaxf(p - 0.2f, 0.f); }
    if (s == -1) { a_ce0b += ce0; a_nbg += 1.f; }
    if (s >= 0) {
      atomicAdd(&ls_inst[s], 1);
      if (cp) {
        float om = 1.f - p;
        float focal = ALPHA_F * om * om * ce1;
        atomicAdd(&ls_sumf[s], focal);
        atomicAdd(&ls_cnt[s], 1);
        atomicMin(&ls_first[s], i);
        int pos = atomicAdd(&wsi[OFF_SCAL + b * 16 + 6], 1);
        if (pos < MCAP) wsi[OFF_CPIDX + b * MCAP + pos] = i;
      }
    }
  }
  __syncthreads();
  // merge per-segment LDS -> global
  atomicAdd(&wsf[OFF_SUMF + b * Kk + tid], ls_sumf[tid]);
  atomicAdd(&wsi[OFF_CNT + b * Kk + tid], ls_cnt[tid]);
  atomicAdd(&wsi[OFF_INST + b * Kk + tid], ls_inst[tid]);
  atomicMin(&wsi[OFF_FIRST + b * Kk + tid], ls_first[tid]);
  // scalar reduce: wave (64) shuffles, then 4 waves via LDS
  for (int o = 32; o > 0; o >>= 1) {
    a_ce0n += __shfl_down(a_ce0n, o);
    a_rpos += __shfl_down(a_rpos, o);
    a_rneg += __shfl_down(a_rneg, o);
    a_ce0b += __shfl_down(a_ce0b, o);
    a_ncp  += __shfl_down(a_ncp, o);
    a_nbg  += __shfl_down(a_nbg, o);
  }
  int wv = tid >> 6;
  if ((tid & 63) == 0) {
    sr[wv][0] = a_ce0n; sr[wv][1] = a_rpos; sr[wv][2] = a_rneg; sr[wv][3] = a_ce0b;
    si[wv][0] = a_ncp;  si[wv][1] = a_nbg;
  }
  __syncthreads();
  if (tid == 0) {
    float s0 = 0, s1 = 0, s2 = 0, s3 = 0, s4 = 0, s5 = 0;
    for (int wq = 0; wq < 4; ++wq) {
      s0 += sr[wq][0]; s1 += sr[wq][1]; s2 += sr[wq][2]; s3 += sr[wq][3];
      s4 += si[wq][0]; s5 += si[wq][1];
    }
    atomicAdd(&wsf[OFF_SCAL + b * 16 + 0], s0);
    atomicAdd(&wsf[OFF_SCAL + b * 16 + 1], s1);
    atomicAdd(&wsf[OFF_SCAL + b * 16 + 2], s2);
    atomicAdd(&wsf[OFF_SCAL + b * 16 + 3], s3);
    atomicAdd(&wsf[OFF_SCAL + b * 16 + 4], s4);
    atomicAdd(&wsf[OFF_SCAL + b * 16 + 5], s5);
  }
}

__global__ __launch_bounds__(256) void k_event(const float* __restrict__ embed,
                                               float* wsf, int* wsi) {
  const int b = blockIdx.x;
  const int t = threadIdx.x;
  int cnt = wsi[OFF_CNT + b * Kk + t];
  int inst = wsi[OFF_INST + b * Kk + t];
  float sf = wsf[OFF_SUMF + b * Kk + t];
  int fi = wsi[OFF_FIRST + b * Kk + t];
  bool has = cnt > 0;
  float w = has ? (float)inst : 0.f;
  float wf = has ? w * (sf / fmaxf((float)cnt, 1.f)) : 0.f;
  if (has) {
    const float4* src = (const float4*)(embed + ((size_t)b * Nn + (size_t)fi) * Dd);
    float4* dst = (float4*)(wsf + OFF_ANCH + ((size_t)b * Kk + t) * Dd);
    dst[0] = src[0]; dst[1] = src[1]; dst[2] = src[2]; dst[3] = src[3];
  }
  for (int o = 32; o > 0; o >>= 1) { w += __shfl_down(w, o); wf += __shfl_down(wf, o); }
  __shared__ float rw[4], rwf[4];
  if ((t & 63) == 0) { rw[t >> 6] = w; rwf[t >> 6] = wf; }
  __syncthreads();
  if (t == 0) {
    float sw = rw[0] + rw[1] + rw[2] + rw[3];
    float swf = rwf[0] + rwf[1] + rwf[2] + rwf[3];
    float pos_bce = swf / fmaxf(sw, 1.f);
    float ce0n = wsf[OFF_SCAL + b * 16 + 0];
    float rpos = wsf[OFF_SCAL + b * 16 + 1];
    float rneg = wsf[OFF_SCAL + b * 16 + 2];
    float ce0b = wsf[OFF_SCAL + b * 16 + 3];
    float ncp  = wsf[OFF_SCAL + b * 16 + 4];
    float nbg  = wsf[OFF_SCAL + b * 16 + 5];
    int mv = wsi[OFF_SCAL + b * 16 + 6];
    float nncp = (float)Nn - ncp;
    float neg_bce = nncp > 0.f ? ce0n / fmaxf(nncp, 1.f) : 0.f;
    float pos_m = rpos / fmaxf(ncp, 1.f);
    float neg_m = nncp > 0.f ? rneg / fmaxf(nncp, 1.f) : 0.f;
    float bg_bce = nbg > 0.f ? ce0b / fmaxf(nbg, 1.f) : 0.f;
    float bl = W_BPOS * pos_bce + W_BNEG * neg_bce + W_BBG * bg_bce + W_MARG * (pos_m + neg_m);
    wsf[OFF_SCAL + b * 16 + 8] = bl;
    float nvalid = (float)Nn - nbg;
    wsi[OFF_SCAL + b * 16 + 7] = (nvalid > 0.f && mv > 0) ? 1 : 0;
  }
}

__global__ __launch_bounds__(256) void k_rep(const float* __restrict__ embed,
                                             float* wsf, int* wsi) {
  const int b = blockIdx.x;
  const int t = threadIdx.x;
  __shared__ int sidx[MCAP];
  __shared__ float colT[256 * Dd];
  __shared__ float ra[4];
  const int mv = wsi[OFF_SCAL + b * 16 + 6];
  const int msel = mv < MSEL ? mv : MSEL;
  const int mload = mv < MCAP ? mv : MCAP;
  for (int i = t; i < MCAP; i += 256)
    sidx[i] = (i < mload) ? wsi[OFF_CPIDX + b * MCAP + i] : 0x7FFFFFFF;
  __syncthreads();
  if (mv > MSEL) {
    // bitonic sort 4096 ints ascending -> smallest-index selection
    for (int ksz = 2; ksz <= MCAP; ksz <<= 1) {
      for (int j = ksz >> 1; j > 0; j >>= 1) {
        for (int e = t; e < MCAP; e += 256) {
          int ixj = e ^ j;
          if (ixj > e) {
            bool up = ((e & ksz) == 0);
            int a = sidx[e], c = sidx[ixj];
            if ((a > c) == up) { sidx[e] = c; sidx[ixj] = a; }
          }
        }
        __syncthreads();
      }
    }
  }
  const float* eb = embed + (size_t)b * Nn * Dd;
  float acc = 0.f;
  for (int r0 = 0; r0 < msel; r0 += 256) {
    int i = r0 + t;
    bool rok = i < msel;
    float e[Dd];
    if (rok) {
      const float4* s = (const float4*)(eb + (size_t)sidx[i] * Dd);
      float4 v0 = s[0], v1 = s[1], v2 = s[2], v3 = s[3];
      e[0]=v0.x; e[1]=v0.y; e[2]=v0.z; e[3]=v0.w;
      e[4]=v1.x; e[5]=v1.y; e[6]=v1.z; e[7]=v1.w;
      e[8]=v2.x; e[9]=v2.y; e[10]=v2.z; e[11]=v2.w;
      e[12]=v3.x; e[13]=v3.y; e[14]=v3.z; e[15]=v3.w;
    }
    for (int c0 = 0; c0 < msel; c0 += 256) {
      int nc = (msel - c0) < 256 ? (msel - c0) : 256;
      __syncthreads();
      for (int c = t; c < nc; c += 256) {
        const float4* s = (const float4*)(eb + (size_t)sidx[c0 + c] * Dd);
        float4* d = (float4*)&colT[c * Dd];
        d[0] = s[0]; d[1] = s[1]; d[2] = s[2]; d[3] = s[3];
      }
      __syncthreads();
      if (rok) {
        for (int c = 0; c < nc; ++c) {
          float d2 = 0.f;
          #pragma unroll
          for (int d = 0; d < Dd; ++d) {
            float df = e[d] - colT[c * Dd + d];
            d2 += df * df;
          }
          acc += __expf(-d2);
        }
      }
    }
  }
  for (int o = 32; o > 0; o >>= 1) acc += __shfl_down(acc, o);
  if ((t & 63) == 0) ra[t >> 6] = acc;
  __syncthreads();
  if (t == 0) {
    float s = ra[0] + ra[1] + ra[2] + ra[3];
    float mvf = (float)mv;
    wsf[OFF_SCAL + b * 16 + 9] = (mv > 1) ? (W_REP * s / fmaxf(mvf * mvf, 1.f)) : 0.f;
  }
}

__global__ __launch_bounds__(256) void k_attr(const float* __restrict__ embed,
                                              const int* __restrict__ sid,
                                              float* wsf, int* wsi) {
  const int b = blockIdx.y;
  const int tid = threadIdx.x;
  __shared__ float anch[Kk * ASTRIDE];   // stride 17 to avoid bank conflicts
  __shared__ int hasf[Kk];
  __shared__ float ld2[Kk];
  const float* ga = wsf + OFF_ANCH + (size_t)b * Kk * Dd;
  for (int i = tid; i < Kk * Dd; i += 256) {
    int k = i >> 4, d = i & 15;
    anch[k * ASTRIDE + d] = ga[i];
  }
  hasf[tid] = (wsi[OFF_CNT + b * Kk + tid] > 0) ? 1 : 0;
  ld2[tid] = 0.f;
  __syncthreads();
  const int base = b * Nn;
  const float* eb = embed + (size_t)base * Dd;
  const int i0 = blockIdx.x * CHUNK;
  for (int it = 0; it < CHUNK / 256; ++it) {
    int i = i0 + it * 256 + tid;
    int s = sid[base + i];
    if (s >= 0 && hasf[s]) {
      const float4* e4 = (const float4*)(eb + (size_t)i * Dd);
      float4 v0 = e4[0], v1 = e4[1], v2 = e4[2], v3 = e4[3];
      const float* a = &anch[s * ASTRIDE];
      float d2 = 0.f, df;
      df = v0.x - a[0];  d2 += df * df;
      df = v0.y - a[1];  d2 += df * df;
      df = v0.z - a[2];  d2 += df * df;
      df = v0.w - a[3];  d2 += df * df;
      df = v1.x - a[4];  d2 += df * df;
      df = v1.y - a[5];  d2 += df * df;
      df = v1.z - a[6];  d2 += df * df;
      df = v1.w - a[7];  d2 += df * df;
      df = v2.x - a[8];  d2 += df * df;
      df = v2.y - a[9];  d2 += df * df;
      df = v2.z - a[10]; d2 += df * df;
      df = v2.w - a[11]; d2 += df * df;
      df = v3.x - a[12]; d2 += df * df;
      df = v3.y - a[13]; d2 += df * df;
      df = v3.z - a[14]; d2 += df * df;
      df = v3.w - a[15]; d2 += df * df;
      atomicAdd(&ld2[s], d2);
    }
  }
  __syncthreads();
  atomicAdd(&wsf[OFF_SD2 + b * Kk + tid], ld2[tid]);
}

__global__ __launch_bounds__(256) void k_final(float* wsf, int* wsi, float* out, int out_size) {
  __shared__ float att[Bn];
  const int t = threadIdx.x;
  if (t < Bn) att[t] = 0.f;
  __syncthreads();
  for (int i = t; i < Bn * Kk; i += 256) {
    int bb = i >> 8;
    if (wsi[OFF_CNT + i] > 0) {
      float inst = (float)wsi[OFF_INST + i];
      float v = wsf[OFF_SD2 + i] / fmaxf(inst, 1.f);
      atomicAdd(&att[bb], v);
    }
  }
  __syncthreads();
  if (t == 0) {
    float total = 0.f;
    int cnt = 0;
    for (int bb = 0; bb < Bn; ++bb) {
      if (wsi[OFF_SCAL + bb * 16 + 7]) {
        total += wsf[OFF_SCAL + bb * 16 + 8] + W_ATTR * att[bb] + wsf[OFF_SCAL + bb * 16 + 9];
        cnt++;
      }
    }
    out[0] = (cnt > 0) ? total / (float)cnt : 0.f;
  }
  // zero any extra output slots (poisoned by harness)
  for (int i = t + 1; i < out_size; i += 256) out[i] = 0.f;
}

extern "C" void kernel_launch(void* const* d_in, const int* in_sizes, int n_in,
                              void* d_out, int out_size, void* d_ws, size_t ws_size,
                              hipStream_t stream) {
  const float* beta = (const float*)d_in[0];
  const float* embed = (const float*)d_in[1];
  const int* sid = (const int*)d_in[2];
  const void* cp = d_in[3];
  float* out = (float*)d_out;
  float* wsf = (float*)d_ws;
  int* wsi = (int*)d_ws;

  k_init<<<128, 256, 0, stream>>>(wsi);
  k_detect<<<256, 256, 0, stream>>>((const unsigned int*)cp, wsi);
  dim3 g1(Nn / CHUNK, Bn);
  k_pass1<<<g1, 256, 0, stream>>>(beta, sid, cp, wsf, wsi);
  k_event<<<Bn, 256, 0, stream>>>(embed, wsf, wsi);
  k_rep<<<Bn, 256, 0, stream>>>(embed, wsf, wsi);
  k_attr<<<g1, 256, 0, stream>>>(embed, sid, wsf, wsi);
  k_final<<<1, 256, 0, stream>>>(wsf, wsi, out, out_size);
}